// Round 14
// baseline (83.803 us; speedup 1.0000x reference)
//
#include <hip/hip_runtime.h>
#include <hip/hip_bf16.h>

#define B 16
#define S 4096
#define D 256
#define U 256
#define ROWS 64
#define NCHK (S / ROWS)  // 64 chunks per batch
#define CPB 2            // chunks per block (pipelined)

typedef short short8 __attribute__((ext_vector_type(8)));
typedef float f32x4 __attribute__((ext_vector_type(4)));

__device__ __forceinline__ ushort f2bf(float f) {
    union { float f; uint u; } x{f};
    uint r = (x.u + 0x7fffu + ((x.u >> 16) & 1u)) >> 16;  // RNE
    return (ushort)r;
}

__device__ __forceinline__ float fast_tanh(float x) {
    float e = __expf(2.0f * x);
    return 1.0f - 2.0f * __builtin_amdgcn_rcpf(e + 1.0f);
}

// KA: fused setup (r13 verbatim).
__global__ void ka_setup(const float* __restrict__ q, const float* __restrict__ W2,
                         const float* __restrict__ b2, const float* __restrict__ b1,
                         const float* __restrict__ W1, float* __restrict__ pqb,
                         ushort* __restrict__ W1p) {
    int bid = blockIdx.x, t = threadIdx.x;
    if (bid < 16) {
        int b = bid, u = t;
        const float* qb = q + b * D;
        float acc = b2[u] + b1[u];
#pragma unroll 8
        for (int d = 0; d < D; ++d)
            acc = fmaf(qb[d], W2[d * U + u], acc);
        pqb[b * U + u] = acc;
    } else {
        int kk = bid - 16;
        int l = t & 63, g = t >> 6;
        int colu0 = l & 15;
        int k0 = kk * 32 + (l >> 4) * 8;
#pragma unroll
        for (int i = 0; i < 4; ++i) {
            int nt = g * 4 + i;
            int colu = nt * 16 + colu0;
            ushort* dst = W1p + (((nt * 8) + kk) * 64 + l) * 8;
#pragma unroll
            for (int e = 0; e < 8; ++e) dst[e] = f2bf(W1[(k0 + e) * U + colu]);
        }
    }
}

// KB: 512 blocks x CPB=2 chunks, double-buffered LDS pipeline:
// while chunk c computes from buf[c&1], chunk c+1's global loads are in flight.
__global__ __launch_bounds__(256, 2) void kb_scores(
    const float* __restrict__ values, const ushort* __restrict__ W1p,
    const float* __restrict__ pqb, const float* __restrict__ V,
    const float* __restrict__ bV, float* __restrict__ cstats,
    float* __restrict__ cpart, float* __restrict__ wout) {
    __shared__ ushort Alds[2][ROWS * 256];  // 2 x 32 KB, XOR-swizzled
    __shared__ float red[4][ROWS];
    __shared__ float wch[ROWS];
    const int bid = blockIdx.x;
    const int t = threadIdx.x;
    const int w = t >> 6, l = t & 63;
    const int lrow = l & 15, lk = l >> 4;
    const int chunk0 = bid * CPB;
    const int b = chunk0 >> 6;  // CPB chunks never straddle a batch

    // hoisted per-thread constants
    float bb[4], vv[4];
#pragma unroll
    for (int nt = 0; nt < 4; ++nt) {
        int u = (w * 4 + nt) * 16 + lrow;
        bb[nt] = pqb[b * U + u];
        vv[nt] = V[u];
    }
    const float bV0 = bV[0];

    // prologue: load chunk0 -> regs, convert -> buf0
    float4 vreg[16];
    {
        const float* src = values + ((size_t)(b * S + (chunk0 & 63) * ROWS)) * D;
#pragma unroll
        for (int i = 0; i < 16; ++i)
            vreg[i] = *(const float4*)&src[(i * 4 + w) * 256 + l * 4];
        char* lds = (char*)Alds[0];
#pragma unroll
        for (int i = 0; i < 16; ++i) {
            int row = i * 4 + w;
            ushort4 h;
            h.x = f2bf(vreg[i].x); h.y = f2bf(vreg[i].y);
            h.z = f2bf(vreg[i].z); h.w = f2bf(vreg[i].w);
            int byte = (row * 512 + l * 8) ^ ((row & 7) << 4);
            *(ushort4*)(lds + byte) = h;
        }
    }

    for (int c = 0; c < CPB; ++c) {
        const int chunk = chunk0 + c;
        const int s0 = (chunk & 63) * ROWS;
        char* lds = (char*)Alds[c & 1];

        // issue next chunk's loads — they fly during this chunk's compute
        if (c + 1 < CPB) {
            const float* src = values + ((size_t)(b * S + ((chunk + 1) & 63) * ROWS)) * D;
#pragma unroll
            for (int i = 0; i < 16; ++i)
                vreg[i] = *(const float4*)&src[(i * 4 + w) * 256 + l * 4];
        }
        __syncthreads();  // buf[c&1] ready for all waves

        // ---- MFMA scores ----
        f32x4 acc[4][4];
#pragma unroll
        for (int mt = 0; mt < 4; ++mt)
#pragma unroll
            for (int nt = 0; nt < 4; ++nt) acc[mt][nt] = (f32x4){0.f, 0.f, 0.f, 0.f};

#pragma unroll
        for (int kk = 0; kk < 8; ++kk) {
            short8 afr[4], bfr[4];
#pragma unroll
            for (int nt = 0; nt < 4; ++nt)
                bfr[nt] = *(const short8*)&W1p[((((w * 4 + nt) * 8) + kk) * 64 + l) * 8];
#pragma unroll
            for (int mt = 0; mt < 4; ++mt) {
                int row = mt * 16 + lrow;
                int byte = (row * 512 + kk * 64 + lk * 16) ^ ((row & 7) << 4);
                afr[mt] = *(const short8*)(lds + byte);
            }
#pragma unroll
            for (int mt = 0; mt < 4; ++mt)
#pragma unroll
                for (int nt = 0; nt < 4; ++nt)
                    acc[mt][nt] = __builtin_amdgcn_mfma_f32_16x16x32_bf16(
                        afr[mt], bfr[nt], acc[mt][nt], 0, 0, 0);
        }

        // ---- epilogue: tanh, .V, reduce over u ----
#pragma unroll
        for (int mt = 0; mt < 4; ++mt) {
#pragma unroll
            for (int r = 0; r < 4; ++r) {
                float s = 0.f;
#pragma unroll
                for (int nt = 0; nt < 4; ++nt)
                    s += fast_tanh(acc[mt][nt][r] + bb[nt]) * vv[nt];
                s += __shfl_xor(s, 1);
                s += __shfl_xor(s, 2);
                s += __shfl_xor(s, 4);
                s += __shfl_xor(s, 8);
                if (lrow == 0) red[w][mt * 16 + lk * 4 + r] = s;
            }
        }
        __syncthreads();

        if (t < ROWS) {  // wave 0: chunk stats + unnormalized weights -> wout
            float s = red[0][t] + red[1][t] + red[2][t] + red[3][t] + bV0;
            float m = s;
#pragma unroll
            for (int off = 32; off; off >>= 1) m = fmaxf(m, __shfl_xor(m, off));
            float z0 = __expf(s - m);
            wch[t] = z0;
            wout[b * S + s0 + t] = z0;  // KC rescales in place
            float z = z0;
#pragma unroll
            for (int off = 32; off; off >>= 1) z += __shfl_xor(z, off);
            if (t == 0) {
                cstats[2 * chunk] = m;
                cstats[2 * chunk + 1] = z;
            }
        }
        __syncthreads();

        // ---- partial context from bf16 LDS: thread t owns column t ----
        union { uint i; float f; } cv;
        float cacc = 0.f;
#pragma unroll 8
        for (int r = 0; r < ROWS; ++r) {
            int byte = (r * 512 + t * 2) ^ ((r & 7) << 4);
            ushort u = *(const ushort*)(lds + byte);
            cv.i = (uint)u << 16;
            cacc = fmaf(wch[r], cv.f, cacc);
        }
        cpart[(size_t)chunk * D + t] = cacc;

        // write next chunk's tile into the other buffer (global loads have landed)
        if (c + 1 < CPB) {
            char* ldsn = (char*)Alds[(c + 1) & 1];
#pragma unroll
            for (int i = 0; i < 16; ++i) {
                int row = i * 4 + w;
                ushort4 h;
                h.x = f2bf(vreg[i].x); h.y = f2bf(vreg[i].y);
                h.z = f2bf(vreg[i].z); h.w = f2bf(vreg[i].w);
                int byte = (row * 512 + l * 8) ^ ((row & 7) << 4);
                *(ushort4*)(ldsn + byte) = h;
            }
        }
        // loop-top __syncthreads publishes buf[(c+1)&1]
    }
}

// KC: finisher, block = (batch b, quarter q); in-place wout rescale (r9-verified).
__global__ void kc_final(const float* __restrict__ cstats, const float* __restrict__ cpart,
                         float* __restrict__ wout, float* __restrict__ ctx) {
    __shared__ float scl[NCHK];
    __shared__ float stats2[2];
    __shared__ float part[4][64];
    int b = blockIdx.x >> 2, q = blockIdx.x & 3;
    int t = threadIdx.x;

    if (t < NCHK) {
        float m = cstats[2 * (b * NCHK + t)];
        float z = cstats[2 * (b * NCHK + t) + 1];
        float M = m;
#pragma unroll
        for (int off = 32; off; off >>= 1) M = fmaxf(M, __shfl_xor(M, off));
        float zz = z * __expf(m - M);
#pragma unroll
        for (int off = 32; off; off >>= 1) zz += __shfl_xor(zz, off);
        scl[t] = __expf(m - M);
        if (t == 0) { stats2[0] = M; stats2[1] = zz; }
    }
    __syncthreads();
    float invZ = 1.0f / stats2[1];

    int tq = t >> 6, dl = t & 63;
    int d = q * 64 + dl;
    float acc = 0.f;
#pragma unroll
    for (int i = 0; i < 16; ++i) {
        int c = tq * 16 + i;
        acc = fmaf(scl[c], cpart[(size_t)(b * NCHK + c) * D + d], acc);
    }
    part[tq][dl] = acc;

#pragma unroll
    for (int i = 0; i < 4; ++i) {
        int ss = q * 1024 + i * 256 + t;
        wout[b * S + ss] *= scl[ss >> 6] * invZ;
    }
    __syncthreads();
    if (t < 64)
        ctx[b * D + q * 64 + t] =
            (part[0][t] + part[1][t] + part[2][t] + part[3][t]) * invZ;
}

extern "C" void kernel_launch(void* const* d_in, const int* in_sizes, int n_in,
                              void* d_out, int out_size, void* d_ws, size_t ws_size,
                              hipStream_t stream) {
    const float* values = (const float*)d_in[0];
    const float* query  = (const float*)d_in[1];
    const float* W1     = (const float*)d_in[2];
    const float* b1     = (const float*)d_in[3];
    const float* W2     = (const float*)d_in[4];
    const float* b2     = (const float*)d_in[5];
    const float* V      = (const float*)d_in[6];
    const float* bV     = (const float*)d_in[7];

    float* out  = (float*)d_out;
    float* ctx  = out;          // [B, D]
    float* wout = out + B * D;  // [B, S, 1]

    float* ws     = (float*)d_ws;
    float* pqb    = ws;                 // B*U          = 4096
    float* cstats = pqb + B * U;        // 2*B*NCHK     = 2048
    float* cpart  = cstats + 2048;      // B*NCHK*D     = 262144
    ushort* W1p   = (ushort*)(cpart + B * NCHK * D);  // 65536 ushorts

    ka_setup<<<24, 256, 0, stream>>>(query, W2, b2, b1, W1, pqb, W1p);
    kb_scores<<<B * NCHK / CPB, 256, 0, stream>>>(values, W1p, pqb, V, bV,
                                                  cstats, cpart, wout);
    kc_final<<<B * 4, 256, 0, stream>>>(cstats, cpart, wout, ctx);
}